// Round 6
// baseline (335.488 us; speedup 1.0000x reference)
//
#include <hip/hip_runtime.h>
#include <hip/hip_bf16.h>

// RNN_41807211659578 R6: 2 barriers/step (dm/error deferred one step),
// register diet (dmv history removed, staging indices hoisted) so the
// 65 weight i64 + transients fit the 256-reg/thread budget (2 waves/SIMD).

typedef unsigned short u16;
typedef unsigned int u32;
typedef unsigned char u8;
typedef long i64;
typedef __attribute__((ext_vector_type(4))) float f32x4;

#define MFMA_F8(acc, a, b) (acc) = __builtin_amdgcn_mfma_f32_16x16x32_fp8_fp8((i64)(a), (i64)(b), (acc), 0, 0, 0)

__device__ __forceinline__ void pin(i64& x) { asm volatile("" : "+v"(x)); }

__device__ __forceinline__ u8 f2e4(float v) {
  return (u8)(__builtin_amdgcn_cvt_pk_fp8_f32(v, 0.f, 0, false) & 0xff);
}
__device__ __forceinline__ u32 pk4(float a, float b, float c, float d) {
  u32 p = (u32)__builtin_amdgcn_cvt_pk_fp8_f32(a, b, 0, false);
  return (u32)__builtin_amdgcn_cvt_pk_fp8_f32(c, d, (int)p, true);
}
__device__ __forceinline__ float sigf(float x) {
  return __builtin_amdgcn_rcpf(1.f + __expf(-x));
}
__device__ __forceinline__ float tanh_fast(float x) {
  return 1.f - 2.f * __builtin_amdgcn_rcpf(1.f + __expf(2.f * x));
}

// ---- workspace layout: wsf floats at base; fp8 weight region at byte 16384 ----
constexpr int E0 = 2 * 384 * 352;      // W0cat [g][384][352] fp8
constexpr int E1 = E0 + 2 * 384 * 256; // W1cat [g][384][256]
constexpr int E2 = E1 + 2 * 128 * 128; // Wn0 (Whh0 n-rows)
constexpr int E3 = E2 + 2 * 128 * 128; // Wn1
constexpr int E4 = E3 + 2 * 128 * 128; // W1 (MLP)
constexpr int E5 = E4 + 2 * 128 * 128; // W2 (MLP)
constexpr int NBIAS = 2048;
constexpr int TOTAL = E5 + NBIAS + 4;
constexpr int WB_BYTE_OFF = 16384;

__global__ void prep_kernel(const float* __restrict__ Wih0, const float* __restrict__ Whh0,
                            const float* __restrict__ bih0, const float* __restrict__ bhh0,
                            const float* __restrict__ Wih1, const float* __restrict__ Whh1,
                            const float* __restrict__ bih1, const float* __restrict__ bhh1,
                            const float* __restrict__ W1, const float* __restrict__ W2,
                            u8* __restrict__ wb, float* __restrict__ wsf) {
  for (int idx = blockIdx.x * blockDim.x + threadIdx.x; idx < TOTAL;
       idx += gridDim.x * blockDim.x) {
    if (idx < E0) {
      int g = idx / 135168;
      int r = idx - g * 135168;
      int j = r / 352;
      int k = r - j * 352;
      const float* wi = Wih0 + (g * 384 + j) * 222;
      float v;
      if (k < 94) v = wi[k];
      else if (k < 96) v = 0.f;
      else if (k < 224) v = wi[k - 2];
      else v = Whh0[(g * 384 + j) * 128 + (k - 224)];
      wb[idx] = f2e4(v);
    } else if (idx < E1) {
      int q = idx - E0;
      int g = q / 98304;
      int r = q - g * 98304;
      int j = r >> 8;
      int k = r & 255;
      float v = (k < 128) ? Wih1[(g * 384 + j) * 128 + k]
                          : Whh1[(g * 384 + j) * 128 + (k - 128)];
      wb[idx] = f2e4(v);
    } else if (idx < E2) {
      int q = idx - E1; int g = q >> 14; int r = q & 16383; int j = r >> 7; int k = r & 127;
      wb[idx] = f2e4(Whh0[(g * 384 + 256 + j) * 128 + k]);
    } else if (idx < E3) {
      int q = idx - E2; int g = q >> 14; int r = q & 16383; int j = r >> 7; int k = r & 127;
      wb[idx] = f2e4(Whh1[(g * 384 + 256 + j) * 128 + k]);
    } else if (idx < E4) {
      int q = idx - E3; int g = q >> 14; int r = q & 16383; int j = r >> 7; int k = r & 127;
      wb[idx] = f2e4(W1[(g * 128 + j) * 128 + k]);
    } else if (idx < E5) {
      int q = idx - E4; int g = q >> 14; int r = q & 16383; int j = r >> 7; int k = r & 127;
      wb[idx] = f2e4(W2[(g * 128 + j) * 128 + k]);
    } else if (idx < E5 + NBIAS) {
      int q = idx - E5;
      float v;
      if (q < 512)       { int g = q >> 8, j = q & 255;              v = bih0[g*384 + j] + bhh0[g*384 + j]; }
      else if (q < 768)  { int p = q - 512;  int g = p >> 7, j = p & 127; v = bih0[g*384 + 256 + j]; }
      else if (q < 1024) { int p = q - 768;  int g = p >> 7, j = p & 127; v = bhh0[g*384 + 256 + j]; }
      else if (q < 1536) { int p = q - 1024; int g = p >> 8, j = p & 255; v = bih1[g*384 + j] + bhh1[g*384 + j]; }
      else if (q < 1792) { int p = q - 1536; int g = p >> 7, j = p & 127; v = bih1[g*384 + 256 + j]; }
      else               { int p = q - 1792; int g = p >> 7, j = p & 127; v = bhh1[g*384 + 256 + j]; }
      wsf[4 + q] = v;
    } else {
      wsf[idx - (E5 + NBIAS)] = 0.f;
    }
  }
}

__global__ __launch_bounds__(512, 2) __attribute__((amdgpu_waves_per_eu(2, 2)))
void rnn_kernel(const float* __restrict__ states,
                const u8* __restrict__ wb,
                float* __restrict__ wsf,
                const float* __restrict__ b1g,
                const float* __restrict__ b2g,
                const float* __restrict__ Wmg,
                const float* __restrict__ bmg) {
  const int blk = blockIdx.x;
  const int g = (blk < 96) ? 0 : 1;
  const int r0 = (g == 0) ? (blk * 32) : ((blk - 96) * 32);
  const int aAg = (g == 0 ? 0 : 12) + (r0 >> 8);
  const int b0 = r0 & 255;

  const int tid = threadIdx.x;
  const int wid = tid >> 6;
  const int ln = tid & 63;
  const int j_in = ln & 15;
  const int kq = ln >> 4;
  const int c0 = wid * 16 + kq * 4;
  const int jh = wid * 16 + j_in;

  __shared__ __align__(16) u8 h0b[2][32 * 136];
  __shared__ __align__(16) u8 h1b[2][32 * 136];
  __shared__ __align__(16) u8 yb[2][32 * 104];
  __shared__ __align__(16) u8 d1b[32 * 136];
  __shared__ __align__(16) u8 d2b[32 * 136];
  __shared__ __align__(16) float bias[1536];
  __shared__ float dmv[32][2];
  __shared__ float red[32][3];

  // ---- weights into registers (65 i64, asm-pinned) ----
  const u8* W0   = wb + g * 135168;
  const u8* W1c  = wb + E0 + g * 98304;
  const u8* Wn0p = wb + E1 + g * 16384;
  const u8* Wn1p = wb + E2 + g * 16384;
  const u8* Wm1p = wb + E3 + g * 16384;
  const u8* Wm2p = wb + E4 + g * 16384;

  i64 w0r[11], w0z[11], w0n[7];
#pragma unroll
  for (int kt = 0; kt < 11; ++kt) {
    w0r[kt] = *(const i64*)(W0 + (jh)       * 352 + kt * 32 + kq * 8);
    w0z[kt] = *(const i64*)(W0 + (128 + jh) * 352 + kt * 32 + kq * 8);
    if (kt < 7) w0n[kt] = *(const i64*)(W0 + (256 + jh) * 352 + kt * 32 + kq * 8);
  }
  i64 w1r[8], w1z[8], w1n[4];
#pragma unroll
  for (int kt = 0; kt < 8; ++kt) {
    w1r[kt] = *(const i64*)(W1c + (jh)       * 256 + kt * 32 + kq * 8);
    w1z[kt] = *(const i64*)(W1c + (128 + jh) * 256 + kt * 32 + kq * 8);
    if (kt < 4) w1n[kt] = *(const i64*)(W1c + (256 + jh) * 256 + kt * 32 + kq * 8);
  }
  i64 wn0[4], wn1[4], wm1[4], wm2[4];
#pragma unroll
  for (int kt = 0; kt < 4; ++kt) {
    wn0[kt] = *(const i64*)(Wn0p + jh * 128 + kt * 32 + kq * 8);
    wn1[kt] = *(const i64*)(Wn1p + jh * 128 + kt * 32 + kq * 8);
    wm1[kt] = *(const i64*)(Wm1p + jh * 128 + kt * 32 + kq * 8);
    wm2[kt] = *(const i64*)(Wm2p + jh * 128 + kt * 32 + kq * 8);
  }
#pragma unroll
  for (int kt = 0; kt < 11; ++kt) { pin(w0r[kt]); pin(w0z[kt]); }
#pragma unroll
  for (int kt = 0; kt < 7; ++kt) pin(w0n[kt]);
#pragma unroll
  for (int kt = 0; kt < 8; ++kt) { pin(w1r[kt]); pin(w1z[kt]); }
#pragma unroll
  for (int kt = 0; kt < 4; ++kt) {
    pin(w1n[kt]); pin(wn0[kt]); pin(wn1[kt]); pin(wm1[kt]); pin(wm2[kt]);
  }

  // ---- biases + Wm into LDS ----
  for (int i = tid; i < 1536; i += 512) {
    float v;
    if (i < 256)       v = wsf[4 + g * 256 + i];
    else if (i < 384)  v = wsf[516 + g * 128 + (i - 256)];
    else if (i < 512)  v = wsf[772 + g * 128 + (i - 384)];
    else if (i < 768)  v = wsf[1028 + g * 256 + (i - 512)];
    else if (i < 896)  v = wsf[1540 + g * 128 + (i - 768)];
    else if (i < 1024) v = wsf[1796 + g * 128 + (i - 896)];
    else if (i < 1152) v = b1g[g * 128 + (i - 1024)];
    else if (i < 1280) v = b2g[g * 128 + (i - 1152)];
    else               v = Wmg[g * 256 + (i - 1280)];
    bias[i] = v;
  }
  for (int i = tid; i < 32 * 136; i += 512) { h0b[0][i] = 0; h1b[0][i] = 0; }

  // ---- hoisted y-staging per-thread constants ----
  // q=0: idx=tid (<768 always since tid<512? no: 512<768 yes); q=1: idx=tid+512, valid if tid<256
  int sI[2], sK[2], sO0[2], sO1[2], sO2[2], sO3[2];
  bool sZ2[2], sZ3[2], sV[2];
#pragma unroll
  for (int q = 0; q < 2; ++q) {
    int idx = tid + q * 512;
    sV[q] = (idx < 768);
    int i = idx / 24, k4 = idx - i * 24;
    sI[q] = i; sK[q] = k4;
    if (k4 == 0) { sO0[q]=aAg*4+2; sO1[q]=aAg*4+3; sO2[q]=0; sO3[q]=1; sZ2[q]=false; sZ3[q]=false; }
    else {
      int kk = k4 * 4 - 2;
      sO0[q]=kk; sO1[q]=kk+1; sO2[q]=kk+2; sO3[q]=kk+3;
      sZ2[q] = (kk+2 >= 92); sZ3[q] = (kk+3 >= 92);
    }
  }
  // stage yb[0] for t=0
#pragma unroll
  for (int q = 0; q < 2; ++q) {
    if (sV[q]) {
      const float* srow = states + ((size_t)(b0 + sI[q])) * 92;
      float v0 = srow[sO0[q]], v1 = srow[sO1[q]];
      float v2 = sZ2[q] ? 0.f : srow[sO2[q]];
      float v3 = sZ3[q] ? 0.f : srow[sO3[q]];
      *(u32*)(&yb[0][sI[q] * 104 + sK[q] * 4]) = pk4(v0, v1, v2, v3);
    }
  }

  const float bm0 = bmg[g * 2], bm1 = bmg[g * 2 + 1];
  f32x4 hv0[2] = {{0,0,0,0},{0,0,0,0}};
  f32x4 hv1[2] = {{0,0,0,0},{0,0,0,0}};
  float accL = 0.f, accEp = 0.f, accEv = 0.f;
  __syncthreads();

  for (int t = 0; t < 48; ++t) {
    const int cur = t & 1, nxt = cur ^ 1;
    const u8* h0c = h0b[cur]; u8* h0n = h0b[nxt];
    const u8* h1c = h1b[cur]; u8* h1n = h1b[nxt];
    const u8* ybc = yb[cur];  u8* ybn = yb[nxt];

    // ==== P1: MLP1(t) + GRU0(t) + h0 writeback + dm(t-1) ====
    // y(t+1) prefetch (consumed in P2)
    float yv0[2], yv1[2], yv2[2], yv3[2];
#pragma unroll
    for (int q = 0; q < 2; ++q) {
      if (sV[q]) {
        const float* srow = states + ((size_t)((t + 1) * 256 + b0 + sI[q])) * 92;
        yv0[q] = srow[sO0[q]]; yv1[q] = srow[sO1[q]];
        yv2[q] = sZ2[q] ? 0.f : srow[sO2[q]];
        yv3[q] = sZ3[q] ? 0.f : srow[sO3[q]];
      }
    }

    const u8* pH1a = h1c + j_in * 136 + kq * 8;
    const u8* pH1b = h1c + (16 + j_in) * 136 + kq * 8;
    const u8* pH0a = h0c + j_in * 136 + kq * 8;
    const u8* pH0b = h0c + (16 + j_in) * 136 + kq * 8;
    const u8* pYa  = ybc + j_in * 104 + kq * 8;
    const u8* pYb  = ybc + (16 + j_in) * 104 + kq * 8;

    // MLP1: d1 = relu(Wm1 x h1 + b1)
    {
      f32x4 m0 = {0,0,0,0}, m1 = {0,0,0,0};
#pragma unroll
      for (int kt = 0; kt < 4; ++kt) {
        i64 bb0 = *(const i64*)(pH1a + kt * 32);
        i64 bb1 = *(const i64*)(pH1b + kt * 32);
        MFMA_F8(m0, wm1[kt], bb0);
        MFMA_F8(m1, wm1[kt], bb1);
      }
      f32x4 b1v = *(const f32x4*)(bias + 1024 + c0);
      *(u32*)(d1b + j_in * 136 + c0) =
        pk4(fmaxf(m0[0]+b1v[0],0.f), fmaxf(m0[1]+b1v[1],0.f), fmaxf(m0[2]+b1v[2],0.f), fmaxf(m0[3]+b1v[3],0.f));
      *(u32*)(d1b + (16 + j_in) * 136 + c0) =
        pk4(fmaxf(m1[0]+b1v[0],0.f), fmaxf(m1[1]+b1v[1],0.f), fmaxf(m1[2]+b1v[2],0.f), fmaxf(m1[3]+b1v[3],0.f));
    }

    // GRU0
    {
      f32x4 aR[2] = {{0,0,0,0},{0,0,0,0}};
      f32x4 aZ[2] = {{0,0,0,0},{0,0,0,0}};
      f32x4 aN[2] = {{0,0,0,0},{0,0,0,0}};
      f32x4 aG[2] = {{0,0,0,0},{0,0,0,0}};
#pragma unroll
      for (int kt = 0; kt < 11; ++kt) {
        i64 bb0, bb1;
        if (kt < 3)      { bb0 = *(const i64*)(pYa + kt * 32);        bb1 = *(const i64*)(pYb + kt * 32); }
        else if (kt < 7) { bb0 = *(const i64*)(pH1a + (kt - 3) * 32); bb1 = *(const i64*)(pH1b + (kt - 3) * 32); }
        else             { bb0 = *(const i64*)(pH0a + (kt - 7) * 32); bb1 = *(const i64*)(pH0b + (kt - 7) * 32); }
        MFMA_F8(aR[0], w0r[kt], bb0); MFMA_F8(aR[1], w0r[kt], bb1);
        MFMA_F8(aZ[0], w0z[kt], bb0); MFMA_F8(aZ[1], w0z[kt], bb1);
        if (kt < 7) { MFMA_F8(aN[0], w0n[kt], bb0); MFMA_F8(aN[1], w0n[kt], bb1); }
        else        { MFMA_F8(aG[0], wn0[kt - 7], bb0); MFMA_F8(aG[1], wn0[kt - 7], bb1); }
      }
      f32x4 brv = *(const f32x4*)(bias + c0);
      f32x4 bzv = *(const f32x4*)(bias + 128 + c0);
      f32x4 biv = *(const f32x4*)(bias + 256 + c0);
      f32x4 bhv = *(const f32x4*)(bias + 384 + c0);
#pragma unroll
      for (int nt = 0; nt < 2; ++nt)
#pragma unroll
        for (int i = 0; i < 4; ++i) {
          float rv = sigf(aR[nt][i] + brv[i]);
          float zv = sigf(aZ[nt][i] + bzv[i]);
          float nv = tanh_fast(aN[nt][i] + biv[i] + rv * (aG[nt][i] + bhv[i]));
          hv0[nt][i] = (1.f - zv) * nv + zv * hv0[nt][i];
        }
#pragma unroll
      for (int nt = 0; nt < 2; ++nt)
        *(u32*)(h0n + (nt * 16 + j_in) * 136 + c0) = pk4(hv0[nt][0], hv0[nt][1], hv0[nt][2], hv0[nt][3]);
    }

    // dm(t-1): reads d2b from step t-1 (garbage at t=0, discarded)
    {
      int row = tid >> 4, c = (tid >> 3) & 1, part = tid & 7;
      const u8* dp = d2b + row * 136 + part * 16;
      const float* wmr = bias + 1280 + c * 128 + part * 16;
      float s = 0.f;
#pragma unroll
      for (int q = 0; q < 4; ++q) {
        u32 w = *(const u32*)(dp + q * 4);
        s += wmr[q * 4 + 0] * __builtin_amdgcn_cvt_f32_fp8((int)w, 0);
        s += wmr[q * 4 + 1] * __builtin_amdgcn_cvt_f32_fp8((int)w, 1);
        s += wmr[q * 4 + 2] * __builtin_amdgcn_cvt_f32_fp8((int)w, 2);
        s += wmr[q * 4 + 3] * __builtin_amdgcn_cvt_f32_fp8((int)w, 3);
      }
      s += __shfl_xor(s, 1); s += __shfl_xor(s, 2); s += __shfl_xor(s, 4);
      if (part == 0) dmv[row][c] = s;
    }
    __syncthreads(); // B1: d1b, h0n, dmv ready

    // ==== P2: error(t-1) + MLP2(t) + GRU1(t) + h1 writeback + y staging ====
    if (t > 0 && tid < 32) {
      const float* sr = states + ((size_t)((t - 1) * 256 + b0 + tid)) * 92 + aAg * 4;
      const float* sn = sr + 256 * 92;
      float dx = dmv[tid][0] + bm0 - sn[2];
      float dy = dmv[tid][1] + bm1 - sn[3];
      float e = sqrtf(dx * dx + dy * dy);
      accL += e;
      if (t - 1 >= 12) {
        accEv += e;
        float ex = sr[0] + 0.1f * sr[2] - sn[0];
        float ey = sr[1] + 0.1f * sr[3] - sn[1];
        accEp += sqrtf(ex * ex + ey * ey);
      }
    }

    // MLP2: d2 = relu(Wm2 x d1 + b2)
    {
      f32x4 m0 = {0,0,0,0}, m1 = {0,0,0,0};
#pragma unroll
      for (int kt = 0; kt < 4; ++kt) {
        i64 bb0 = *(const i64*)(d1b + j_in * 136 + kt * 32 + kq * 8);
        i64 bb1 = *(const i64*)(d1b + (16 + j_in) * 136 + kt * 32 + kq * 8);
        MFMA_F8(m0, wm2[kt], bb0);
        MFMA_F8(m1, wm2[kt], bb1);
      }
      f32x4 b2v = *(const f32x4*)(bias + 1152 + c0);
      *(u32*)(d2b + j_in * 136 + c0) =
        pk4(fmaxf(m0[0]+b2v[0],0.f), fmaxf(m0[1]+b2v[1],0.f), fmaxf(m0[2]+b2v[2],0.f), fmaxf(m0[3]+b2v[3],0.f));
      *(u32*)(d2b + (16 + j_in) * 136 + c0) =
        pk4(fmaxf(m1[0]+b2v[0],0.f), fmaxf(m1[1]+b2v[1],0.f), fmaxf(m1[2]+b2v[2],0.f), fmaxf(m1[3]+b2v[3],0.f));
    }

    // GRU1: reads h0n (new) + h1c (old)
    {
      f32x4 aR[2] = {{0,0,0,0},{0,0,0,0}};
      f32x4 aZ[2] = {{0,0,0,0},{0,0,0,0}};
      f32x4 aN[2] = {{0,0,0,0},{0,0,0,0}};
      f32x4 aG[2] = {{0,0,0,0},{0,0,0,0}};
      const u8* pG0a = h0n + j_in * 136 + kq * 8;
      const u8* pG0b = h0n + (16 + j_in) * 136 + kq * 8;
#pragma unroll
      for (int kt = 0; kt < 8; ++kt) {
        i64 bb0, bb1;
        if (kt < 4) { bb0 = *(const i64*)(pG0a + kt * 32);        bb1 = *(const i64*)(pG0b + kt * 32); }
        else        { bb0 = *(const i64*)(pH1a + (kt - 4) * 32);  bb1 = *(const i64*)(pH1b + (kt - 4) * 32); }
        MFMA_F8(aR[0], w1r[kt], bb0); MFMA_F8(aR[1], w1r[kt], bb1);
        MFMA_F8(aZ[0], w1z[kt], bb0); MFMA_F8(aZ[1], w1z[kt], bb1);
        if (kt < 4) { MFMA_F8(aN[0], w1n[kt], bb0); MFMA_F8(aN[1], w1n[kt], bb1); }
        else        { MFMA_F8(aG[0], wn1[kt - 4], bb0); MFMA_F8(aG[1], wn1[kt - 4], bb1); }
      }
      f32x4 brv = *(const f32x4*)(bias + 512 + c0);
      f32x4 bzv = *(const f32x4*)(bias + 640 + c0);
      f32x4 biv = *(const f32x4*)(bias + 768 + c0);
      f32x4 bhv = *(const f32x4*)(bias + 896 + c0);
#pragma unroll
      for (int nt = 0; nt < 2; ++nt)
#pragma unroll
        for (int i = 0; i < 4; ++i) {
          float rv = sigf(aR[nt][i] + brv[i]);
          float zv = sigf(aZ[nt][i] + bzv[i]);
          float nv = tanh_fast(aN[nt][i] + biv[i] + rv * (aG[nt][i] + bhv[i]));
          hv1[nt][i] = (1.f - zv) * nv + zv * hv1[nt][i];
        }
#pragma unroll
      for (int nt = 0; nt < 2; ++nt)
        *(u32*)(h1n + (nt * 16 + j_in) * 136 + c0) = pk4(hv1[nt][0], hv1[nt][1], hv1[nt][2], hv1[nt][3]);
    }

    // y(t+1) staging
#pragma unroll
    for (int q = 0; q < 2; ++q) {
      if (sV[q]) {
        *(u32*)(ybn + sI[q] * 104 + sK[q] * 4) = pk4(yv0[q], yv1[q], yv2[q], yv3[q]);
      }
    }
    __syncthreads(); // B2
  }

  // ==== tail: dm(47) + error(47) ====
  {
    int row = tid >> 4, c = (tid >> 3) & 1, part = tid & 7;
    const u8* dp = d2b + row * 136 + part * 16;
    const float* wmr = bias + 1280 + c * 128 + part * 16;
    float s = 0.f;
#pragma unroll
    for (int q = 0; q < 4; ++q) {
      u32 w = *(const u32*)(dp + q * 4);
      s += wmr[q * 4 + 0] * __builtin_amdgcn_cvt_f32_fp8((int)w, 0);
      s += wmr[q * 4 + 1] * __builtin_amdgcn_cvt_f32_fp8((int)w, 1);
      s += wmr[q * 4 + 2] * __builtin_amdgcn_cvt_f32_fp8((int)w, 2);
      s += wmr[q * 4 + 3] * __builtin_amdgcn_cvt_f32_fp8((int)w, 3);
    }
    s += __shfl_xor(s, 1); s += __shfl_xor(s, 2); s += __shfl_xor(s, 4);
    if (part == 0) dmv[row][c] = s;
  }
  __syncthreads();
  if (tid < 32) {
    const float* sr = states + ((size_t)(47 * 256 + b0 + tid)) * 92 + aAg * 4;
    const float* sn = sr + 256 * 92;
    float dx = dmv[tid][0] + bm0 - sn[2];
    float dy = dmv[tid][1] + bm1 - sn[3];
    float e = sqrtf(dx * dx + dy * dy);
    accL += e;
    accEv += e;
    float ex = sr[0] + 0.1f * sr[2] - sn[0];
    float ey = sr[1] + 0.1f * sr[3] - sn[1];
    accEp += sqrtf(ex * ex + ey * ey);
    red[tid][0] = accL; red[tid][1] = accEp; red[tid][2] = accEv;
  }
  __syncthreads();
  if (tid < 3) {
    float s = 0.f;
    for (int i = 0; i < 32; ++i) s += red[i][tid];
    atomicAdd(&wsf[tid], s);
  }
}

__global__ void fin_kernel(const float* __restrict__ wacc, float* __restrict__ out) {
  if (threadIdx.x == 0 && blockIdx.x == 0) {
    out[0] = wacc[0] / 1104.f;
    out[1] = wacc[1] / 828.f;
    out[2] = wacc[2] / 828.f;
  }
}

extern "C" void kernel_launch(void* const* d_in, const int* in_sizes, int n_in,
                              void* d_out, int out_size, void* d_ws, size_t ws_size,
                              hipStream_t stream) {
  const float* states = (const float*)d_in[0];
  const float* Wih0 = (const float*)d_in[1];
  const float* Whh0 = (const float*)d_in[2];
  const float* bih0 = (const float*)d_in[3];
  const float* bhh0 = (const float*)d_in[4];
  const float* Wih1 = (const float*)d_in[5];
  const float* Whh1 = (const float*)d_in[6];
  const float* bih1 = (const float*)d_in[7];
  const float* bhh1 = (const float*)d_in[8];
  const float* W1   = (const float*)d_in[9];
  const float* b1   = (const float*)d_in[10];
  const float* W2   = (const float*)d_in[11];
  const float* b2   = (const float*)d_in[12];
  const float* Wm   = (const float*)d_in[13];
  const float* bm   = (const float*)d_in[14];

  float* wsf = (float*)d_ws;
  u8* wb = (u8*)d_ws + WB_BYTE_OFF;

  int prep_blocks = (TOTAL + 255) / 256;
  prep_kernel<<<prep_blocks, 256, 0, stream>>>(Wih0, Whh0, bih0, bhh0,
                                               Wih1, Whh1, bih1, bhh1,
                                               W1, W2, wb, wsf);
  rnn_kernel<<<184, 512, 0, stream>>>(states, wb, wsf, b1, b2, Wm, bm);
  fin_kernel<<<1, 64, 0, stream>>>(wsf, (float*)d_out);
}